// Round 2
// baseline (590.913 us; speedup 1.0000x reference)
//
#include <hip/hip_runtime.h>
#include <hip/hip_bf16.h>
#include <cstdint>
#include <cstddef>

// ---------------------------------------------------------------------------
// SelfAttention: qkv = x@Wqkv^T ; P' = exp(Q@K^T*0.125) ; l = rowsum(P') ;
// O' = P'@V ; y = (O'@Wout^T)/l + b.  bf16 MFMA GEMMs (fp32 accum).
// R6: single-barrier 8-phase pipeline. vs R5: frag ds_reads are issued ONE
// PHASE AHEAD into double-buffered af[2]/bfr[2] registers, so LDS latency
// hides under the MFMA cluster; no inline lgkmcnt/sched_barrier (compiler
// emits the counted lgkmcnt itself); ONE s_barrier per phase (was 2);
// uniform vmcnt(6) per phase. Plane lifecycle (verified): staged at n,
// vmcnt-certified by n+3 end (+barrier), read-issued >= n+4, used n+5..n+6,
// overwritten >= 2 phases after last read-issue.
// ---------------------------------------------------------------------------

typedef __bf16 bf16x8 __attribute__((ext_vector_type(8)));
typedef float f32x4 __attribute__((ext_vector_type(4)));

__device__ __forceinline__ void gl_lds16(const void* g, void* l) {
  __builtin_amdgcn_global_load_lds((const __attribute__((address_space(1))) void*)g,
                                   (__attribute__((address_space(3))) void*)l, 16, 0, 0);
}

// ---------------- cast fp32 -> bf16, 8 elems/thread ----------------
__global__ __launch_bounds__(256) void cast_f32_bf16(const float* __restrict__ in,
                                                     __hip_bfloat16* __restrict__ out, int n) {
  int i = (blockIdx.x * 256 + threadIdx.x) * 8;
  if (i >= n) return;
  float4 a = *(const float4*)(in + i);
  float4 b = *(const float4*)(in + i + 4);
  __align__(16) __hip_bfloat16 o[8];
  o[0] = __float2bfloat16(a.x); o[1] = __float2bfloat16(a.y);
  o[2] = __float2bfloat16(a.z); o[3] = __float2bfloat16(a.w);
  o[4] = __float2bfloat16(b.x); o[5] = __float2bfloat16(b.y);
  o[6] = __float2bfloat16(b.z); o[7] = __float2bfloat16(b.w);
  *(uint4*)(out + i) = *(const uint4*)o;
}

// ============ shared GEMM core: 256x256 tile, BK=64, pipelined phases ======
// LDS planes (elems): A plane p -> p*8192 ; B plane p -> 32768 + p*8192.
// Plane p holds one K-slice (32 cols) of a 256-row panel: [256 rows][32 elems],
// chunk (row r, slot s) holds global k-chunk s ^ ((r>>1)&3) (source-side
// swizzle, linear LDS dest for global_load_lds; 0 bank conflicts measured).

// Stage one 16KiB unit (A or B panel K-slice KS of tile TT):
#define STAGE_(SRCP, OFFS, LDSBASE, TT, KS)                                        \
  if ((TT) < NT) {                                                                 \
    const int kb_ = (TT) * 64 + (KS) * 32;                                         \
    _Pragma("unroll") for (int i = 0; i < 2; ++i)                                  \
      gl_lds16((SRCP) + OFFS[i] + kb_,                                             \
               sm + (LDSBASE) + (size_t)(tid + 512 * i) * 8);                      \
  }

// Issue next-phase fragment loads (double-buffered registers, static indices).
#define LDA_FRAGS(BUF, APL, CH)                                                    \
  _Pragma("unroll") for (int mi = 0; mi < 4; ++mi)                                 \
    af[BUF][mi] = *(const bf16x8*)(sm + (APL) * 8192 + arow + ((CH) * 4 + mi) * 512);
#define LDB_FRAGS(BUF, BPL)                                                        \
  _Pragma("unroll") for (int ni = 0; ni < 4; ++ni)                                 \
    bfr[BUF][ni] = *(const bf16x8*)(sm + 32768 + (BPL) * 8192 + brow + ni * 512);

// 16 MFMA on the CURRENT frag buffers (compiler inserts counted lgkmcnt).
#define MFMA16(AB, BB, CH)                                                         \
  __builtin_amdgcn_s_setprio(1);                                                   \
  _Pragma("unroll") for (int mi = 0; mi < 4; ++mi)                                 \
    _Pragma("unroll") for (int ni = 0; ni < 4; ++ni)                               \
      acc[(CH) * 4 + mi][ni] = __builtin_amdgcn_mfma_f32_16x16x32_bf16(            \
          af[AB][mi], bfr[BB][ni], acc[(CH) * 4 + mi][ni], 0, 0, 0);               \
  __builtin_amdgcn_s_setprio(0);

// Phase end: counted vmcnt (3 phases x 2 loads in flight), ONE barrier.
#define PHEND()                                                                    \
  asm volatile("s_waitcnt vmcnt(6)" ::: "memory");                                 \
  __builtin_amdgcn_s_barrier();

// C = A @ B^T ; A:[M,K] bf16 lda, B:[N,K] bf16 ldb (row-major over K).
// NT must be even (all shapes here: K in {1024,2048} -> NT in {16,32}).
#define GEMM_CORE256(APTR, LDA, BPTR, LDB, KLEN)                                   \
  __shared__ __align__(16) __hip_bfloat16 sm[65536]; /* 128 KiB */                 \
  const __hip_bfloat16* Abase_ = (APTR);                                           \
  const __hip_bfloat16* Bbase_ = (BPTR);                                           \
  const int tid  = threadIdx.x;                                                    \
  const int lane = tid & 63;                                                       \
  const int q    = lane >> 4;                                                      \
  const int m16  = lane & 15;                                                      \
  const int wave = tid >> 6;                                                       \
  const int wr   = wave >> 2;                                                      \
  const int wc   = wave & 3;                                                       \
  const int row0 = blockIdx.y * 256;                                               \
  const int col0 = blockIdx.x * 256;                                               \
  unsigned srcA[2], srcB[2];                                                       \
  _Pragma("unroll") for (int i = 0; i < 2; ++i) {                                  \
    const int c_ = tid + 512 * i;                                                  \
    const int r_ = c_ >> 2;                                                        \
    const int kc_ = ((c_ & 3) ^ ((r_ >> 1) & 3)) * 8;                              \
    srcA[i] = (unsigned)(row0 + r_) * (unsigned)(LDA) + (unsigned)kc_;             \
    srcB[i] = (unsigned)(col0 + r_) * (unsigned)(LDB) + (unsigned)kc_;             \
  }                                                                                \
  const int NT = (KLEN) >> 6;                                                      \
  f32x4 acc[8][4];                                                                 \
  { const f32x4 z_ = {0.f, 0.f, 0.f, 0.f};                                         \
    _Pragma("unroll") for (int i = 0; i < 8; ++i)                                  \
      _Pragma("unroll") for (int j = 0; j < 4; ++j) acc[i][j] = z_; }              \
  const int soff = (q ^ ((m16 >> 1) & 3)) * 8;                                     \
  const int arow = (wr * 128 + m16) * 32 + soff;                                   \
  const int brow = (wc * 64 + m16) * 32 + soff;                                    \
  bf16x8 af[2][4], bfr[2][4];                                                      \
  /* prologue: planes 0,1 <- t0.{ks0,ks1}; plane2 <- t1.ks0 (12 loads/wave) */     \
  STAGE_(Abase_, srcA, 0,             0, 0)                                        \
  STAGE_(Bbase_, srcB, 32768,         0, 0)                                        \
  STAGE_(Abase_, srcA, 8192,          0, 1)                                        \
  STAGE_(Bbase_, srcB, 32768 + 8192,  0, 1)                                        \
  STAGE_(Abase_, srcA, 16384,         1, 0)                                        \
  STAGE_(Bbase_, srcB, 32768 + 16384, 1, 0)                                        \
  asm volatile("s_waitcnt vmcnt(8)" ::: "memory"); /* plane0 certified */          \
  __builtin_amdgcn_s_barrier();                                                    \
  LDA_FRAGS(0, 0, 0) LDB_FRAGS(0, 0)  /* frags for P0 */                           \
  for (int t = 0; t < NT; t += 2) {                                                \
    /* P0: mfma pl0.ch0 | issue pl0.ch1 | stage A-pl3 <- (t+1).ks1 */              \
    LDA_FRAGS(1, 0, 1)                 STAGE_(Abase_, srcA, 24576,         t+1, 1) \
    MFMA16(0, 0, 0) PHEND()                                                        \
    /* P1: mfma pl0.ch1 | issue pl1.ch0 + B-pl1 | stage B-pl3 */                   \
    LDA_FRAGS(0, 1, 0) LDB_FRAGS(1, 1) STAGE_(Bbase_, srcB, 32768 + 24576, t+1, 1) \
    MFMA16(1, 0, 1) PHEND()                                                        \
    /* P2: mfma pl1.ch0 | issue pl1.ch1 | stage A-pl0 <- (t+2).ks0 */              \
    LDA_FRAGS(1, 1, 1)                 STAGE_(Abase_, srcA, 0,             t+2, 0) \
    MFMA16(0, 1, 0) PHEND()                                                        \
    /* P3: mfma pl1.ch1 | issue pl2.ch0 + B-pl2 | stage B-pl0 */                   \
    LDA_FRAGS(0, 2, 0) LDB_FRAGS(0, 2) STAGE_(Bbase_, srcB, 32768,         t+2, 0) \
    MFMA16(1, 1, 1) PHEND()                                                        \
    /* P4: mfma pl2.ch0 | issue pl2.ch1 | stage A-pl1 <- (t+2).ks1 */              \
    LDA_FRAGS(1, 2, 1)                 STAGE_(Abase_, srcA, 8192,          t+2, 1) \
    MFMA16(0, 0, 0) PHEND()                                                        \
    /* P5: mfma pl2.ch1 | issue pl3.ch0 + B-pl3 | stage B-pl1 */                   \
    LDA_FRAGS(0, 3, 0) LDB_FRAGS(1, 3) STAGE_(Bbase_, srcB, 32768 + 8192,  t+2, 1) \
    MFMA16(1, 0, 1) PHEND()                                                        \
    /* P6: mfma pl3.ch0 | issue pl3.ch1 | stage A-pl2 <- (t+3).ks0 */              \
    LDA_FRAGS(1, 3, 1)                 STAGE_(Abase_, srcA, 16384,         t+3, 0) \
    MFMA16(0, 1, 0) PHEND()                                                        \
    /* P7: mfma pl3.ch1 | issue next-pair pl0.ch0 + B-pl0 | stage B-pl2 */         \
    LDA_FRAGS(0, 0, 0) LDB_FRAGS(0, 0) STAGE_(Bbase_, srcB, 32768 + 16384, t+3, 0) \
    MFMA16(1, 1, 1) PHEND()                                                        \
  }                                                                                \
  /* C/D layout (m89/m91): col = lane&15, row = (lane>>4)*4 + reg */               \
  const int crow = row0 + wr * 128 + q * 4;                                        \
  const int ccol = col0 + wc * 64 + m16;

// ---------------- batched gemm ----------------
// OUT_MODE: 0 = bf16 out; 2 = f32 out * (1/rsum[row]) + bias[col]
template<int OUT_MODE>
__global__ __launch_bounds__(512) void gemm_bt(
    const __hip_bfloat16* __restrict__ A, int lda, long long sA,
    const __hip_bfloat16* __restrict__ B, int ldb, long long sB,
    void* __restrict__ Cv, int ldc, long long sC,
    const float* __restrict__ bias, const float* __restrict__ rsum, int K)
{
  const int bz = blockIdx.z;
  GEMM_CORE256(A + (size_t)bz * sA, lda, B + (size_t)bz * sB, ldb, K)
  if constexpr (OUT_MODE == 0) {
    __hip_bfloat16* C = (__hip_bfloat16*)Cv + (size_t)bz * sC;
    #pragma unroll
    for (int mi = 0; mi < 8; ++mi)
      #pragma unroll
      for (int ni = 0; ni < 4; ++ni)
        #pragma unroll
        for (int r = 0; r < 4; ++r)
          C[(size_t)(crow + mi * 16 + r) * ldc + ccol + ni * 16] = __float2bfloat16(acc[mi][ni][r]);
  } else {
    float* C = (float*)Cv + (size_t)bz * sC;
    float bv[4];
    #pragma unroll
    for (int ni = 0; ni < 4; ++ni) bv[ni] = bias[ccol + ni * 16];
    #pragma unroll
    for (int mi = 0; mi < 8; ++mi) {
      float sc[4];
      #pragma unroll
      for (int r = 0; r < 4; ++r) sc[r] = 1.f / rsum[crow + mi * 16 + r];
      #pragma unroll
      for (int ni = 0; ni < 4; ++ni)
        #pragma unroll
        for (int r = 0; r < 4; ++r)
          C[(size_t)(crow + mi * 16 + r) * ldc + ccol + ni * 16] =
              acc[mi][ni][r] * sc[r] + bv[ni];
    }
  }
}

// ---------------- QK^T gemm, fused exp epilogue + atomic row sums ----------------
// P' = exp(acc*0.125) (bf16); Lsum[row] += rowsum of the bf16-rounded P' tile.
__global__ __launch_bounds__(512) void gemm_qk_exp(
    const __hip_bfloat16* __restrict__ A, int lda, long long sA,
    const __hip_bfloat16* __restrict__ B, int ldb, long long sB,
    __hip_bfloat16* __restrict__ Pv, int ldc, long long sC,
    float* __restrict__ Lsum, int ldl, int K)
{
  const int bz = blockIdx.z;
  GEMM_CORE256(A + (size_t)bz * sA, lda, B + (size_t)bz * sB, ldb, K)
  __hip_bfloat16* C = Pv + (size_t)bz * sC;
  float* Lrow = Lsum + (size_t)bz * ldl;
  #pragma unroll
  for (int mi = 0; mi < 8; ++mi) {
    #pragma unroll
    for (int r = 0; r < 4; ++r) {
      float s = 0.f;
      #pragma unroll
      for (int ni = 0; ni < 4; ++ni) {
        const float e = __expf(acc[mi][ni][r] * 0.125f);
        const __hip_bfloat16 h = __float2bfloat16(e);
        C[(size_t)(crow + mi * 16 + r) * ldc + ccol + ni * 16] = h;
        s += __bfloat162float(h);
      }
      // reduce across the 16 lanes of this q-group (cols), then 1 atomic/row/wave
      #pragma unroll
      for (int mask = 1; mask < 16; mask <<= 1) s += __shfl_xor(s, mask);
      if (m16 == 0) atomicAdd(&Lrow[crow + mi * 16 + r], s);
    }
  }
}

// ---------------- QKV gemm with split epilogue ----------------
// Cols 0..2047 (Q,K) -> QK [M, 2048] bf16. Cols 2048..3071 (V) -> Vt [1024, M]
// (transposed). Branch is block-uniform (blockIdx.x < 8 => Q/K, >= 8 => V).
__global__ __launch_bounds__(512) void gemm_qkv(
    const __hip_bfloat16* __restrict__ A, int lda,
    const __hip_bfloat16* __restrict__ B, int ldb,
    __hip_bfloat16* __restrict__ QK,
    __hip_bfloat16* __restrict__ Vt, int M, int K)
{
  GEMM_CORE256(A, lda, B, ldb, K)
  if (blockIdx.x < 8) {
    #pragma unroll
    for (int mi = 0; mi < 8; ++mi)
      #pragma unroll
      for (int ni = 0; ni < 4; ++ni)
        #pragma unroll
        for (int r = 0; r < 4; ++r)
          QK[(size_t)(crow + mi * 16 + r) * 2048 + ccol + ni * 16] = __float2bfloat16(acc[mi][ni][r]);
  } else {
    #pragma unroll
    for (int mi = 0; mi < 8; ++mi) {
      const int rowbase = crow + mi * 16;  // multiple of 4 -> 8B-aligned dest
      #pragma unroll
      for (int ni = 0; ni < 4; ++ni) {
        const int vc = ccol + ni * 16 - 2048;
        __align__(8) __hip_bfloat16 o[4];
        #pragma unroll
        for (int r = 0; r < 4; ++r) o[r] = __float2bfloat16(acc[mi][ni][r]);
        *(uint2*)(Vt + (size_t)vc * M + rowbase) = *(const uint2*)o;
      }
    }
  }
}

// ---------------------------------------------------------------------------
extern "C" void kernel_launch(void* const* d_in, const int* in_sizes, int n_in,
                              void* d_out, int out_size, void* d_ws, size_t ws_size,
                              hipStream_t stream) {
  const float* x     = (const float*)d_in[0];   // [8, 2048, 1024]
  const float* w_qkv = (const float*)d_in[1];   // [3072, 1024]
  const float* w_out = (const float*)d_in[2];   // [1024, 1024]
  const float* b_out = (const float*)d_in[3];   // [1024]
  float* out = (float*)d_out;

  constexpr int Bz = 8, N = 2048, D = 1024, E = 3 * D;
  constexpr int M = Bz * N;  // 16384

  // ---- workspace: fixed regions + one dynamic region (aliased) ----
  // fixed: Wo(2.1) + Vt(33.5) + QK(67.1) + AO(33.5) + L(64K) ~ 136.3 MB
  // dynamic: phase1 Xb(33.5)+Wq(6.3)=39.8 ; phases 2-4 P'(G*8.4)
  char* p = (char*)d_ws;
  __hip_bfloat16* Wo = (__hip_bfloat16*)p; p += (size_t)D * D * 2;
  __hip_bfloat16* Vt = (__hip_bfloat16*)p; p += (size_t)D * M * 2;
  __hip_bfloat16* QK = (__hip_bfloat16*)p; p += (size_t)M * 2 * D * 2;
  __hip_bfloat16* AO = (__hip_bfloat16*)p; p += (size_t)M * D * 2;
  float*          L  = (float*)p;          p += (size_t)M * 4;
  char* dyn = p;
  const size_t fixed_sz = (size_t)(dyn - (char*)d_ws);
  const size_t xw_sz = (size_t)M * D * 2 + (size_t)E * D * 2;  // Xb + Wq

  int G = 1;
  for (int g = 8; g >= 1; g >>= 1) {
    size_t dyn_sz = (size_t)g * N * N * 2;  // P' bf16
    if (dyn_sz < xw_sz) dyn_sz = xw_sz;
    if (fixed_sz + dyn_sz <= ws_size) { G = g; break; }
  }

  __hip_bfloat16* Xb = (__hip_bfloat16*)dyn;
  __hip_bfloat16* Wq = (__hip_bfloat16*)(dyn + (size_t)M * D * 2);
  __hip_bfloat16* P  = (__hip_bfloat16*)dyn;

  // phase 1: casts + QKV projection (+ zero the row-sum accumulator)
  hipMemsetAsync(L, 0, (size_t)M * 4, stream);
  cast_f32_bf16<<<(M * D) / (8 * 256), 256, 0, stream>>>(x, Xb, M * D);
  cast_f32_bf16<<<(E * D) / (8 * 256), 256, 0, stream>>>(w_qkv, Wq, E * D);
  cast_f32_bf16<<<(D * D) / (8 * 256), 256, 0, stream>>>(w_out, Wo, D * D);
  gemm_qkv<<<dim3(E / 256, M / 256), 512, 0, stream>>>(Xb, D, Wq, D, QK, Vt, M, D);

  // phases 2-3: batched attention, groups of G
  for (int g = 0; g < Bz / G; ++g) {
    const __hip_bfloat16* Qg = QK + (size_t)g * G * N * (2 * D);
    // P' = exp(Q @ K^T * 0.125) (bf16) + atomic row sums into L
    gemm_qk_exp<<<dim3(N / 256, N / 256, G), 512, 0, stream>>>(
        Qg, 2 * D, (long long)N * 2 * D,
        Qg + D, 2 * D, (long long)N * 2 * D,
        P, N, (long long)N * N,
        L + (size_t)g * G * N, N, D);
    // O' = P' @ Vt^T (bf16, unnormalized)
    gemm_bt<0><<<dim3(D / 256, N / 256, G), 512, 0, stream>>>(
        P, N, (long long)N * N,
        Vt + (size_t)g * G * N, M, (long long)N,
        AO + (size_t)g * G * N * D, D, (long long)N * D,
        nullptr, nullptr, N);
  }

  // phase 4: y = (O' @ Wout^T) / l[row] + b
  gemm_bt<2><<<dim3(D / 256, M / 256, 1), 512, 0, stream>>>(
      AO, D, 0LL, Wo, D, 0LL, out, D, 0LL, b_out, L, D);
}

// Round 3
// 418.567 us; speedup vs baseline: 1.4118x; 1.4118x over previous
//
#include <hip/hip_runtime.h>
#include <hip/hip_bf16.h>
#include <cstdint>
#include <cstddef>

// ---------------------------------------------------------------------------
// SelfAttention: qkv = x@Wqkv^T ; P' = exp(Q@K^T*0.125) ; l = rowsum(P') ;
// O' = P'@V ; y = (O'@Wout^T)/l + b.  bf16 MFMA GEMMs (fp32 accum).
// R7: single-barrier phases. vs R5 (best, 426us): ONE s_barrier per phase
// (was 2) and NO lgkmcnt(0)/sched_barrier drain-wall before the MFMA cluster
// -- frag ds_reads issue at phase start and the compiler inserts fine-grained
// lgkmcnt so MFMA0 starts after 2 reads, not 8. vs R6 (spilled, 591us): no
// cross-phase frag registers (af[4]+bfr[4] only, intra-phase live).
// Ordering fences: vmcnt asm (memory clobber) blocks sinking below phase end;
// sched_barrier(0) after each s_barrier blocks hoisting above phase start.
// Unit queue (simulated): 4 units (8 loads) in flight steady-state, vmcnt(8)
// retires 1 unit/phase, each plane certified exactly 1 phase before read,
// overwrites land >=1 barrier after last read. Peeled tail pair drains with
// vmcnt 8,8,6,4,2,0.
// ---------------------------------------------------------------------------

typedef __bf16 bf16x8 __attribute__((ext_vector_type(8)));
typedef float f32x4 __attribute__((ext_vector_type(4)));

__device__ __forceinline__ void gl_lds16(const void* g, void* l) {
  __builtin_amdgcn_global_load_lds((const __attribute__((address_space(1))) void*)g,
                                   (__attribute__((address_space(3))) void*)l, 16, 0, 0);
}

// ---------------- cast fp32 -> bf16, 8 elems/thread ----------------
__global__ __launch_bounds__(256) void cast_f32_bf16(const float* __restrict__ in,
                                                     __hip_bfloat16* __restrict__ out, int n) {
  int i = (blockIdx.x * 256 + threadIdx.x) * 8;
  if (i >= n) return;
  float4 a = *(const float4*)(in + i);
  float4 b = *(const float4*)(in + i + 4);
  __align__(16) __hip_bfloat16 o[8];
  o[0] = __float2bfloat16(a.x); o[1] = __float2bfloat16(a.y);
  o[2] = __float2bfloat16(a.z); o[3] = __float2bfloat16(a.w);
  o[4] = __float2bfloat16(b.x); o[5] = __float2bfloat16(b.y);
  o[6] = __float2bfloat16(b.z); o[7] = __float2bfloat16(b.w);
  *(uint4*)(out + i) = *(const uint4*)o;
}

// ============ shared GEMM core: 256x256 tile, BK=64, single-barrier phases ==
// LDS planes (elems): A plane p -> p*8192 ; B plane p -> 32768 + p*8192.
// Plane = one K-slice (32 elems) of a 256-row panel [256][32]; chunk (row r,
// slot s) holds global k-chunk s ^ ((r>>1)&3) (source-side swizzle, linear
// LDS dest for global_load_lds; 0 bank conflicts measured in R5).

// Stage ONE 16KiB unit (A or B panel, K-slice KS of tile TT): 2 loads/thread.
#define ST1(SRCP, OFFS, LDSBASE, TT, KS)                                           \
  { const int kb_ = (TT) * 64 + (KS) * 32;                                         \
    _Pragma("unroll") for (int i = 0; i < 2; ++i)                                  \
      gl_lds16((SRCP) + OFFS[i] + kb_,                                             \
               sm + (LDSBASE) + (size_t)(tid + 512 * i) * 8); }

// Frag reads for this phase (intra-phase registers only).
#define LDAF(APL, CH)                                                              \
  _Pragma("unroll") for (int mi = 0; mi < 4; ++mi)                                 \
    af[mi] = *(const bf16x8*)(sm + (APL) * 8192 + arow + ((CH) * 4 + mi) * 512);
#define LDBF(BPL)                                                                  \
  _Pragma("unroll") for (int ni = 0; ni < 4; ++ni)                                 \
    bfr[ni] = *(const bf16x8*)(sm + 32768 + (BPL) * 8192 + brow + ni * 512);

// 16 MFMA; compiler inserts fine-grained lgkmcnt between reads and uses.
#define MF16(CH)                                                                   \
  __builtin_amdgcn_s_setprio(1);                                                   \
  _Pragma("unroll") for (int mi = 0; mi < 4; ++mi)                                 \
    _Pragma("unroll") for (int ni = 0; ni < 4; ++ni)                               \
      acc[(CH) * 4 + mi][ni] = __builtin_amdgcn_mfma_f32_16x16x32_bf16(            \
          af[mi], bfr[ni], acc[(CH) * 4 + mi][ni], 0, 0, 0);                       \
  __builtin_amdgcn_s_setprio(0);

// Phase end: counted vmcnt (memory clobber = sink fence), ONE barrier,
// sched_barrier(0) = hoist fence for the next phase's ds_reads.
#define ENDP(VMN)                                                                  \
  asm volatile("s_waitcnt vmcnt(" #VMN ")" ::: "memory");                          \
  __builtin_amdgcn_s_barrier();                                                    \
  __builtin_amdgcn_sched_barrier(0);
#define ENDB()                                                                     \
  __builtin_amdgcn_s_barrier();                                                    \
  __builtin_amdgcn_sched_barrier(0);

// C = A @ B^T ; A:[M,K] bf16 lda, B:[N,K] bf16 ldb (row-major over K).
// NT = K/64 must be even and >= 4 (shapes here: K in {1024,2048}).
#define GEMM_CORE256(APTR, LDA, BPTR, LDB, KLEN)                                   \
  __shared__ __align__(16) __hip_bfloat16 sm[65536]; /* 128 KiB */                 \
  const __hip_bfloat16* Abase_ = (APTR);                                           \
  const __hip_bfloat16* Bbase_ = (BPTR);                                           \
  const int tid  = threadIdx.x;                                                    \
  const int lane = tid & 63;                                                       \
  const int q    = lane >> 4;                                                      \
  const int m16  = lane & 15;                                                      \
  const int wave = tid >> 6;                                                       \
  const int wr   = wave >> 2;                                                      \
  const int wc   = wave & 3;                                                       \
  const int row0 = blockIdx.y * 256;                                               \
  const int col0 = blockIdx.x * 256;                                               \
  unsigned srcA[2], srcB[2];                                                       \
  _Pragma("unroll") for (int i = 0; i < 2; ++i) {                                  \
    const int c_ = tid + 512 * i;                                                  \
    const int r_ = c_ >> 2;                                                        \
    const int kc_ = ((c_ & 3) ^ ((r_ >> 1) & 3)) * 8;                              \
    srcA[i] = (unsigned)(row0 + r_) * (unsigned)(LDA) + (unsigned)kc_;             \
    srcB[i] = (unsigned)(col0 + r_) * (unsigned)(LDB) + (unsigned)kc_;             \
  }                                                                                \
  const int NT = (KLEN) >> 6;                                                      \
  f32x4 acc[8][4];                                                                 \
  { const f32x4 z_ = {0.f, 0.f, 0.f, 0.f};                                         \
    _Pragma("unroll") for (int i = 0; i < 8; ++i)                                  \
      _Pragma("unroll") for (int j = 0; j < 4; ++j) acc[i][j] = z_; }              \
  const int soff = (q ^ ((m16 >> 1) & 3)) * 8;                                     \
  const int arow = (wr * 128 + m16) * 32 + soff;                                   \
  const int brow = (wc * 64 + m16) * 32 + soff;                                    \
  bf16x8 af[4], bfr[4];                                                            \
  /* prologue: planes 0,1 <- t0.{ks0,ks1}; plane2 <- t1.ks0 (12 loads/wave) */     \
  ST1(Abase_, srcA, 0,             0, 0)                                           \
  ST1(Bbase_, srcB, 32768,         0, 0)                                           \
  ST1(Abase_, srcA, 8192,          0, 1)                                           \
  ST1(Bbase_, srcB, 32768 + 8192,  0, 1)                                           \
  ST1(Abase_, srcA, 16384,         1, 0)                                           \
  ST1(Bbase_, srcB, 32768 + 16384, 1, 0)                                           \
  ENDP(8) /* certifies plane0 (first 4 loads) for all waves */                     \
  for (int t = 0; t < NT - 2; t += 2) {                                            \
    LDAF(0,0) LDBF(0) ST1(Abase_, srcA, 24576,         t+1, 1) MF16(0) ENDP(8)     \
    LDAF(0,1)         ST1(Bbase_, srcB, 32768 + 24576, t+1, 1) MF16(1) ENDP(8)     \
    LDAF(1,0) LDBF(1) ST1(Abase_, srcA, 0,             t+2, 0) MF16(0) ENDP(8)     \
    LDAF(1,1)         ST1(Bbase_, srcB, 32768,         t+2, 0) MF16(1) ENDP(8)     \
    LDAF(2,0) LDBF(2) ST1(Abase_, srcA, 8192,          t+2, 1) MF16(0) ENDP(8)     \
    LDAF(2,1)         ST1(Bbase_, srcB, 32768 + 8192,  t+2, 1) MF16(1) ENDP(8)     \
    LDAF(3,0) LDBF(3) ST1(Abase_, srcA, 16384,         t+3, 0) MF16(0) ENDP(8)     \
    LDAF(3,1)         ST1(Bbase_, srcB, 32768 + 16384, t+3, 0) MF16(1) ENDP(8)     \
  }                                                                                \
  /* peeled tail pair (tiles NT-2, NT-1): stage only plane3, drain queue */        \
  LDAF(0,0) LDBF(0) ST1(Abase_, srcA, 24576,         NT-1, 1) MF16(0) ENDP(8)      \
  LDAF(0,1)         ST1(Bbase_, srcB, 32768 + 24576, NT-1, 1) MF16(1) ENDP(8)      \
  LDAF(1,0) LDBF(1)                                           MF16(0) ENDP(6)      \
  LDAF(1,1)                                                   MF16(1) ENDP(4)      \
  LDAF(2,0) LDBF(2)                                           MF16(0) ENDP(2)      \
  LDAF(2,1)                                                   MF16(1) ENDP(0)      \
  LDAF(3,0) LDBF(3)                                           MF16(0) ENDB()       \
  LDAF(3,1)                                                   MF16(1)              \
  /* C/D layout (m89/m91): col = lane&15, row = (lane>>4)*4 + reg */               \
  const int crow = row0 + wr * 128 + q * 4;                                        \
  const int ccol = col0 + wc * 64 + m16;

// ---------------- batched gemm ----------------
// OUT_MODE: 0 = bf16 out; 2 = f32 out * (1/rsum[row]) + bias[col]
template<int OUT_MODE>
__global__ __launch_bounds__(512) void gemm_bt(
    const __hip_bfloat16* __restrict__ A, int lda, long long sA,
    const __hip_bfloat16* __restrict__ B, int ldb, long long sB,
    void* __restrict__ Cv, int ldc, long long sC,
    const float* __restrict__ bias, const float* __restrict__ rsum, int K)
{
  const int bz = blockIdx.z;
  GEMM_CORE256(A + (size_t)bz * sA, lda, B + (size_t)bz * sB, ldb, K)
  if constexpr (OUT_MODE == 0) {
    __hip_bfloat16* C = (__hip_bfloat16*)Cv + (size_t)bz * sC;
    #pragma unroll
    for (int mi = 0; mi < 8; ++mi)
      #pragma unroll
      for (int ni = 0; ni < 4; ++ni)
        #pragma unroll
        for (int r = 0; r < 4; ++r)
          C[(size_t)(crow + mi * 16 + r) * ldc + ccol + ni * 16] = __float2bfloat16(acc[mi][ni][r]);
  } else {
    float* C = (float*)Cv + (size_t)bz * sC;
    float bv[4];
    #pragma unroll
    for (int ni = 0; ni < 4; ++ni) bv[ni] = bias[ccol + ni * 16];
    #pragma unroll
    for (int mi = 0; mi < 8; ++mi) {
      float sc[4];
      #pragma unroll
      for (int r = 0; r < 4; ++r) sc[r] = 1.f / rsum[crow + mi * 16 + r];
      #pragma unroll
      for (int ni = 0; ni < 4; ++ni)
        #pragma unroll
        for (int r = 0; r < 4; ++r)
          C[(size_t)(crow + mi * 16 + r) * ldc + ccol + ni * 16] =
              acc[mi][ni][r] * sc[r] + bv[ni];
    }
  }
}

// ---------------- QK^T gemm, fused exp epilogue + atomic row sums ----------------
// P' = exp(acc*0.125) (bf16); Lsum[row] += rowsum of the bf16-rounded P' tile.
__global__ __launch_bounds__(512) void gemm_qk_exp(
    const __hip_bfloat16* __restrict__ A, int lda, long long sA,
    const __hip_bfloat16* __restrict__ B, int ldb, long long sB,
    __hip_bfloat16* __restrict__ Pv, int ldc, long long sC,
    float* __restrict__ Lsum, int ldl, int K)
{
  const int bz = blockIdx.z;
  GEMM_CORE256(A + (size_t)bz * sA, lda, B + (size_t)bz * sB, ldb, K)
  __hip_bfloat16* C = Pv + (size_t)bz * sC;
  float* Lrow = Lsum + (size_t)bz * ldl;
  #pragma unroll
  for (int mi = 0; mi < 8; ++mi) {
    #pragma unroll
    for (int r = 0; r < 4; ++r) {
      float s = 0.f;
      #pragma unroll
      for (int ni = 0; ni < 4; ++ni) {
        const float e = __expf(acc[mi][ni][r] * 0.125f);
        const __hip_bfloat16 h = __float2bfloat16(e);
        C[(size_t)(crow + mi * 16 + r) * ldc + ccol + ni * 16] = h;
        s += __bfloat162float(h);
      }
      // reduce across the 16 lanes of this q-group (cols), then 1 atomic/row/wave
      #pragma unroll
      for (int mask = 1; mask < 16; mask <<= 1) s += __shfl_xor(s, mask);
      if (m16 == 0) atomicAdd(&Lrow[crow + mi * 16 + r], s);
    }
  }
}

// ---------------- QKV gemm with split epilogue ----------------
// Cols 0..2047 (Q,K) -> QK [M, 2048] bf16. Cols 2048..3071 (V) -> Vt [1024, M]
// (transposed). Branch is block-uniform (blockIdx.x < 8 => Q/K, >= 8 => V).
__global__ __launch_bounds__(512) void gemm_qkv(
    const __hip_bfloat16* __restrict__ A, int lda,
    const __hip_bfloat16* __restrict__ B, int ldb,
    __hip_bfloat16* __restrict__ QK,
    __hip_bfloat16* __restrict__ Vt, int M, int K)
{
  GEMM_CORE256(A, lda, B, ldb, K)
  if (blockIdx.x < 8) {
    #pragma unroll
    for (int mi = 0; mi < 8; ++mi)
      #pragma unroll
      for (int ni = 0; ni < 4; ++ni)
        #pragma unroll
        for (int r = 0; r < 4; ++r)
          QK[(size_t)(crow + mi * 16 + r) * 2048 + ccol + ni * 16] = __float2bfloat16(acc[mi][ni][r]);
  } else {
    #pragma unroll
    for (int mi = 0; mi < 8; ++mi) {
      const int rowbase = crow + mi * 16;  // multiple of 4 -> 8B-aligned dest
      #pragma unroll
      for (int ni = 0; ni < 4; ++ni) {
        const int vc = ccol + ni * 16 - 2048;
        __align__(8) __hip_bfloat16 o[4];
        #pragma unroll
        for (int r = 0; r < 4; ++r) o[r] = __float2bfloat16(acc[mi][ni][r]);
        *(uint2*)(Vt + (size_t)vc * M + rowbase) = *(const uint2*)o;
      }
    }
  }
}

// ---------------------------------------------------------------------------
extern "C" void kernel_launch(void* const* d_in, const int* in_sizes, int n_in,
                              void* d_out, int out_size, void* d_ws, size_t ws_size,
                              hipStream_t stream) {
  const float* x     = (const float*)d_in[0];   // [8, 2048, 1024]
  const float* w_qkv = (const float*)d_in[1];   // [3072, 1024]
  const float* w_out = (const float*)d_in[2];   // [1024, 1024]
  const float* b_out = (const float*)d_in[3];   // [1024]
  float* out = (float*)d_out;

  constexpr int Bz = 8, N = 2048, D = 1024, E = 3 * D;
  constexpr int M = Bz * N;  // 16384

  // ---- workspace: fixed regions + one dynamic region (aliased) ----
  // fixed: Wo(2.1) + Vt(33.5) + QK(67.1) + AO(33.5) + L(64K) ~ 136.3 MB
  // dynamic: phase1 Xb(33.5)+Wq(6.3)=39.8 ; phases 2-4 P'(G*8.4)
  char* p = (char*)d_ws;
  __hip_bfloat16* Wo = (__hip_bfloat16*)p; p += (size_t)D * D * 2;
  __hip_bfloat16* Vt = (__hip_bfloat16*)p; p += (size_t)D * M * 2;
  __hip_bfloat16* QK = (__hip_bfloat16*)p; p += (size_t)M * 2 * D * 2;
  __hip_bfloat16* AO = (__hip_bfloat16*)p; p += (size_t)M * D * 2;
  float*          L  = (float*)p;          p += (size_t)M * 4;
  char* dyn = p;
  const size_t fixed_sz = (size_t)(dyn - (char*)d_ws);
  const size_t xw_sz = (size_t)M * D * 2 + (size_t)E * D * 2;  // Xb + Wq

  int G = 1;
  for (int g = 8; g >= 1; g >>= 1) {
    size_t dyn_sz = (size_t)g * N * N * 2;  // P' bf16
    if (dyn_sz < xw_sz) dyn_sz = xw_sz;
    if (fixed_sz + dyn_sz <= ws_size) { G = g; break; }
  }

  __hip_bfloat16* Xb = (__hip_bfloat16*)dyn;
  __hip_bfloat16* Wq = (__hip_bfloat16*)(dyn + (size_t)M * D * 2);
  __hip_bfloat16* P  = (__hip_bfloat16*)dyn;

  // phase 1: casts + QKV projection (+ zero the row-sum accumulator)
  hipMemsetAsync(L, 0, (size_t)M * 4, stream);
  cast_f32_bf16<<<(M * D) / (8 * 256), 256, 0, stream>>>(x, Xb, M * D);
  cast_f32_bf16<<<(E * D) / (8 * 256), 256, 0, stream>>>(w_qkv, Wq, E * D);
  cast_f32_bf16<<<(D * D) / (8 * 256), 256, 0, stream>>>(w_out, Wo, D * D);
  gemm_qkv<<<dim3(E / 256, M / 256), 512, 0, stream>>>(Xb, D, Wq, D, QK, Vt, M, D);

  // phases 2-3: batched attention, groups of G
  for (int g = 0; g < Bz / G; ++g) {
    const __hip_bfloat16* Qg = QK + (size_t)g * G * N * (2 * D);
    // P' = exp(Q @ K^T * 0.125) (bf16) + atomic row sums into L
    gemm_qk_exp<<<dim3(N / 256, N / 256, G), 512, 0, stream>>>(
        Qg, 2 * D, (long long)N * 2 * D,
        Qg + D, 2 * D, (long long)N * 2 * D,
        P, N, (long long)N * N,
        L + (size_t)g * G * N, N, D);
    // O' = P' @ Vt^T (bf16, unnormalized)
    gemm_bt<0><<<dim3(D / 256, N / 256, G), 512, 0, stream>>>(
        P, N, (long long)N * N,
        Vt + (size_t)g * G * N, M, (long long)N,
        AO + (size_t)g * G * N * D, D, (long long)N * D,
        nullptr, nullptr, N);
  }

  // phase 4: y = (O' @ Wout^T) / l[row] + b
  gemm_bt<2><<<dim3(D / 256, M / 256, 1), 512, 0, stream>>>(
      AO, D, 0LL, Wo, D, 0LL, out, D, 0LL, b_out, L, D);
}

// Round 4
// 375.856 us; speedup vs baseline: 1.5722x; 1.1136x over previous
//
#include <hip/hip_runtime.h>
#include <hip/hip_bf16.h>
#include <cstdint>
#include <cstddef>

// ---------------------------------------------------------------------------
// SelfAttention via pre-contracted weights (full-dim attention, no head split):
//   W~T = Wk^T Wq ; Wc = Wo Wv        (1024^2, computed on 128^2-tile core)
//   Qx  = X @ W~  ; Vc = X @ Wc^T     (fused one pass, V stored transposed)
//   P'  = exp(Qx @ X^T * 0.125) ; l = rowsum(P')
//   y   = (P' @ Vc)/l + b             (PV epilogue writes final f32 out)
// Removes the K-projection third of qkv AND the whole out-projection pass:
// 275 -> 206 GF of M-sized GEMMs. Big GEMMs use the R7 single-barrier
// 256x256/BK=64 core (39% MfmaUtil, no spill) -- unchanged this round.
// ---------------------------------------------------------------------------

typedef __bf16 bf16x8 __attribute__((ext_vector_type(8)));
typedef float f32x4 __attribute__((ext_vector_type(4)));

__device__ __forceinline__ void gl_lds16(const void* g, void* l) {
  __builtin_amdgcn_global_load_lds((const __attribute__((address_space(1))) void*)g,
                                   (__attribute__((address_space(3))) void*)l, 16, 0, 0);
}

// ---------------- cast fp32 -> bf16, 8 elems/thread ----------------
__global__ __launch_bounds__(256) void cast_f32_bf16(const float* __restrict__ in,
                                                     __hip_bfloat16* __restrict__ out, int n) {
  int i = (blockIdx.x * 256 + threadIdx.x) * 8;
  if (i >= n) return;
  float4 a = *(const float4*)(in + i);
  float4 b = *(const float4*)(in + i + 4);
  __align__(16) __hip_bfloat16 o[8];
  o[0] = __float2bfloat16(a.x); o[1] = __float2bfloat16(a.y);
  o[2] = __float2bfloat16(a.z); o[3] = __float2bfloat16(a.w);
  o[4] = __float2bfloat16(b.x); o[5] = __float2bfloat16(b.y);
  o[6] = __float2bfloat16(b.z); o[7] = __float2bfloat16(b.w);
  *(uint4*)(out + i) = *(const uint4*)o;
}

// ---------------- transpose-cast: w_qkv mat z (f32 [1024,1024]) -> bf16 ^T --
// z=0: Wq -> slot2 (WqT), z=1: Wk -> slot0 (WkT), z=2: Wv -> slot3 (WvT).
__global__ __launch_bounds__(256) void tcast(const float* __restrict__ w_qkv,
                                             __hip_bfloat16* __restrict__ wsb) {
  __shared__ float t[64][65];
  const int z = blockIdx.z;
  const int zo = (z == 0) ? 2 : ((z == 1) ? 0 : 3);
  const float* src = w_qkv + (size_t)z * 1024 * 1024;
  __hip_bfloat16* dst = wsb + (size_t)zo * 1024 * 1024;
  const int r0 = blockIdx.y * 64, c0 = blockIdx.x * 64;
  const int tid = threadIdx.x;
  const int lr = tid >> 2, lc4 = tid & 3;
  #pragma unroll
  for (int j = 0; j < 4; ++j) {
    float4 v = *(const float4*)(src + (size_t)(r0 + lr) * 1024 + c0 + lc4 * 16 + j * 4);
    t[lr][lc4 * 16 + j * 4 + 0] = v.x;
    t[lr][lc4 * 16 + j * 4 + 1] = v.y;
    t[lr][lc4 * 16 + j * 4 + 2] = v.z;
    t[lr][lc4 * 16 + j * 4 + 3] = v.w;
  }
  __syncthreads();
  const int oc = tid >> 2;
  #pragma unroll
  for (int s2 = 0; s2 < 2; ++s2) {
    const int s = (tid & 3) + s2 * 4;
    __align__(16) __hip_bfloat16 o[8];
    #pragma unroll
    for (int j = 0; j < 8; ++j) o[j] = __float2bfloat16(t[s * 8 + j][oc]);
    *(uint4*)(dst + (size_t)(c0 + oc) * 1024 + r0 + s * 8) = *(const uint4*)o;
  }
}

// ============ small GEMM core: 128x128 tile, BK=64 (proven R4 core) ========
#define GEMM_CORE64(APTR, LDA, BPTR, LDB, KLEN)                                    \
  __shared__ __align__(16) __hip_bfloat16 As[128 * 64];                            \
  __shared__ __align__(16) __hip_bfloat16 Bs[128 * 64];                            \
  const int tid  = threadIdx.x;                                                    \
  const int lane = tid & 63;                                                       \
  const int q    = lane >> 4;                                                      \
  const int m16  = lane & 15;                                                      \
  const int wave = tid >> 6;                                                       \
  const int wr   = wave >> 1;                                                      \
  const int wc   = wave & 1;                                                       \
  const int row0 = blockIdx.y * 128;                                               \
  const int col0 = blockIdx.x * 128;                                               \
  unsigned offA[4], offB[4];                                                       \
  _Pragma("unroll") for (int i = 0; i < 4; ++i) {                                  \
    const int c = tid + 256 * i;                                                   \
    const int r = c >> 3, kc = ((c ^ (c >> 3)) & 7) * 8;                           \
    offA[i] = (unsigned)(row0 + r) * (unsigned)(LDA) + kc;                         \
    offB[i] = (unsigned)(col0 + r) * (unsigned)(LDB) + kc;                         \
  }                                                                                \
  const f32x4 zeroS = {0.f, 0.f, 0.f, 0.f};                                        \
  f32x4 acc[4][4];                                                                 \
  _Pragma("unroll") for (int i = 0; i < 4; ++i)                                    \
    _Pragma("unroll") for (int j = 0; j < 4; ++j) acc[i][j] = zeroS;               \
  const int sl0 = (q ^ (m16 & 7)) * 8;                                             \
  for (int k0 = 0; k0 < (KLEN); k0 += 64) {                                        \
    _Pragma("unroll") for (int i = 0; i < 4; ++i) {                                \
      gl_lds16((APTR) + offA[i] + k0, As + ((size_t)tid + 256 * i) * 8);           \
      gl_lds16((BPTR) + offB[i] + k0, Bs + ((size_t)tid + 256 * i) * 8);           \
    }                                                                              \
    __syncthreads();                                                               \
    _Pragma("unroll") for (int step = 0; step < 2; ++step) {                       \
      const int so = sl0 ^ (step * 32);                                            \
      bf16x8 af[4], bfr[4];                                                        \
      _Pragma("unroll") for (int mi = 0; mi < 4; ++mi)                             \
        af[mi] = *(const bf16x8*)(As + (wr * 64 + mi * 16 + m16) * 64 + so);       \
      _Pragma("unroll") for (int ni = 0; ni < 4; ++ni)                             \
        bfr[ni] = *(const bf16x8*)(Bs + (wc * 64 + ni * 16 + m16) * 64 + so);      \
      _Pragma("unroll") for (int mi = 0; mi < 4; ++mi)                             \
        _Pragma("unroll") for (int ni = 0; ni < 4; ++ni)                           \
          acc[mi][ni] = __builtin_amdgcn_mfma_f32_16x16x32_bf16(af[mi], bfr[ni],   \
                                                                acc[mi][ni],0,0,0);\
    }                                                                              \
    __syncthreads();                                                               \
  }                                                                                \
  const int crow = row0 + wr * 64 + q * 4;                                         \
  const int ccol = col0 + wc * 64 + m16;

// batched small gemm, bf16 out: C = A @ B^T
__global__ __launch_bounds__(256) void gemm_small(
    const __hip_bfloat16* __restrict__ A, int lda, long long sA,
    const __hip_bfloat16* __restrict__ B, int ldb, long long sB,
    __hip_bfloat16* __restrict__ Cv, int ldc, long long sC, int K)
{
  const int bz = blockIdx.z;
  GEMM_CORE64(A + (size_t)bz * sA, lda, B + (size_t)bz * sB, ldb, K)
  __hip_bfloat16* C = Cv + (size_t)bz * sC;
  #pragma unroll
  for (int mi = 0; mi < 4; ++mi)
    #pragma unroll
    for (int ni = 0; ni < 4; ++ni)
      #pragma unroll
      for (int r = 0; r < 4; ++r)
        C[(size_t)(crow + mi * 16 + r) * ldc + ccol + ni * 16] = __float2bfloat16(acc[mi][ni][r]);
}

// ============ big GEMM core: 256x256 tile, BK=64, single-barrier phases ====
// (R7 core, unchanged: planes [256][32], source-side XOR swizzle, gload_lds
//  width 16, counted vmcnt(8), one barrier per phase, peeled 2-tile tail.)
#define ST1(SRCP, OFFS, LDSBASE, TT, KS)                                           \
  { const int kb_ = (TT) * 64 + (KS) * 32;                                         \
    _Pragma("unroll") for (int i = 0; i < 2; ++i)                                  \
      gl_lds16((SRCP) + OFFS[i] + kb_,                                             \
               sm + (LDSBASE) + (size_t)(tid + 512 * i) * 8); }

#define LDAF(APL, CH)                                                              \
  _Pragma("unroll") for (int mi = 0; mi < 4; ++mi)                                 \
    af[mi] = *(const bf16x8*)(sm + (APL) * 8192 + arow + ((CH) * 4 + mi) * 512);
#define LDBF(BPL)                                                                  \
  _Pragma("unroll") for (int ni = 0; ni < 4; ++ni)                                 \
    bfr[ni] = *(const bf16x8*)(sm + 32768 + (BPL) * 8192 + brow + ni * 512);

#define MF16(CH)                                                                   \
  __builtin_amdgcn_s_setprio(1);                                                   \
  _Pragma("unroll") for (int mi = 0; mi < 4; ++mi)                                 \
    _Pragma("unroll") for (int ni = 0; ni < 4; ++ni)                               \
      acc[(CH) * 4 + mi][ni] = __builtin_amdgcn_mfma_f32_16x16x32_bf16(            \
          af[mi], bfr[ni], acc[(CH) * 4 + mi][ni], 0, 0, 0);                       \
  __builtin_amdgcn_s_setprio(0);

#define ENDP(VMN)                                                                  \
  asm volatile("s_waitcnt vmcnt(" #VMN ")" ::: "memory");                          \
  __builtin_amdgcn_s_barrier();                                                    \
  __builtin_amdgcn_sched_barrier(0);
#define ENDB()                                                                     \
  __builtin_amdgcn_s_barrier();                                                    \
  __builtin_amdgcn_sched_barrier(0);

#define GEMM_CORE256(APTR, LDA, BPTR, LDB, KLEN)                                   \
  __shared__ __align__(16) __hip_bfloat16 sm[65536]; /* 128 KiB */                 \
  const __hip_bfloat16* Abase_ = (APTR);                                           \
  const __hip_bfloat16* Bbase_ = (BPTR);                                           \
  const int tid  = threadIdx.x;                                                    \
  const int lane = tid & 63;                                                       \
  const int q    = lane >> 4;                                                      \
  const int m16  = lane & 15;                                                      \
  const int wave = tid >> 6;                                                       \
  const int wr   = wave >> 2;                                                      \
  const int wc   = wave & 3;                                                       \
  const int row0 = blockIdx.y * 256;                                               \
  const int col0 = blockIdx.x * 256;                                               \
  unsigned srcA[2], srcB[2];                                                       \
  _Pragma("unroll") for (int i = 0; i < 2; ++i) {                                  \
    const int c_ = tid + 512 * i;                                                  \
    const int r_ = c_ >> 2;                                                        \
    const int kc_ = ((c_ & 3) ^ ((r_ >> 1) & 3)) * 8;                              \
    srcA[i] = (unsigned)(row0 + r_) * (unsigned)(LDA) + (unsigned)kc_;             \
    srcB[i] = (unsigned)(col0 + r_) * (unsigned)(LDB) + (unsigned)kc_;             \
  }                                                                                \
  const int NT = (KLEN) >> 6;                                                      \
  f32x4 acc[8][4];                                                                 \
  { const f32x4 z_ = {0.f, 0.f, 0.f, 0.f};                                         \
    _Pragma("unroll") for (int i = 0; i < 8; ++i)                                  \
      _Pragma("unroll") for (int j = 0; j < 4; ++j) acc[i][j] = z_; }              \
  const int soff = (q ^ ((m16 >> 1) & 3)) * 8;                                     \
  const int arow = (wr * 128 + m16) * 32 + soff;                                   \
  const int brow = (wc * 64 + m16) * 32 + soff;                                    \
  bf16x8 af[4], bfr[4];                                                            \
  ST1(Abase_, srcA, 0,             0, 0)                                           \
  ST1(Bbase_, srcB, 32768,         0, 0)                                           \
  ST1(Abase_, srcA, 8192,          0, 1)                                           \
  ST1(Bbase_, srcB, 32768 + 8192,  0, 1)                                           \
  ST1(Abase_, srcA, 16384,         1, 0)                                           \
  ST1(Bbase_, srcB, 32768 + 16384, 1, 0)                                           \
  ENDP(8)                                                                          \
  for (int t = 0; t < NT - 2; t += 2) {                                            \
    LDAF(0,0) LDBF(0) ST1(Abase_, srcA, 24576,         t+1, 1) MF16(0) ENDP(8)     \
    LDAF(0,1)         ST1(Bbase_, srcB, 32768 + 24576, t+1, 1) MF16(1) ENDP(8)     \
    LDAF(1,0) LDBF(1) ST1(Abase_, srcA, 0,             t+2, 0) MF16(0) ENDP(8)     \
    LDAF(1,1)         ST1(Bbase_, srcB, 32768,         t+2, 0) MF16(1) ENDP(8)     \
    LDAF(2,0) LDBF(2) ST1(Abase_, srcA, 8192,          t+2, 1) MF16(0) ENDP(8)     \
    LDAF(2,1)         ST1(Bbase_, srcB, 32768 + 8192,  t+2, 1) MF16(1) ENDP(8)     \
    LDAF(3,0) LDBF(3) ST1(Abase_, srcA, 16384,         t+3, 0) MF16(0) ENDP(8)     \
    LDAF(3,1)         ST1(Bbase_, srcB, 32768 + 16384, t+3, 0) MF16(1) ENDP(8)     \
  }                                                                                \
  LDAF(0,0) LDBF(0) ST1(Abase_, srcA, 24576,         NT-1, 1) MF16(0) ENDP(8)      \
  LDAF(0,1)         ST1(Bbase_, srcB, 32768 + 24576, NT-1, 1) MF16(1) ENDP(8)      \
  LDAF(1,0) LDBF(1)                                           MF16(0) ENDP(6)      \
  LDAF(1,1)                                                   MF16(1) ENDP(4)      \
  LDAF(2,0) LDBF(2)                                           MF16(0) ENDP(2)      \
  LDAF(2,1)                                                   MF16(1) ENDP(0)      \
  LDAF(3,0) LDBF(3)                                           MF16(0) ENDB()       \
  LDAF(3,1)                                                   MF16(1)              \
  const int crow = row0 + wr * 128 + q * 4;                                        \
  const int ccol = col0 + wc * 64 + m16;

// ---------------- Qx/Vc fused projection ----------------
// B = [W~T ; Wc] (2048 rows). blockIdx.x<4 -> Qx[m,0..1023] bf16;
// x>=4 -> Vt[(col-1024), m] transposed bf16.
__global__ __launch_bounds__(512) void gemm_qv(
    const __hip_bfloat16* __restrict__ A, int lda,
    const __hip_bfloat16* __restrict__ B, int ldb,
    __hip_bfloat16* __restrict__ Qx,
    __hip_bfloat16* __restrict__ Vt, int M, int K)
{
  GEMM_CORE256(A, lda, B, ldb, K)
  if (blockIdx.x < 4) {
    #pragma unroll
    for (int mi = 0; mi < 8; ++mi)
      #pragma unroll
      for (int ni = 0; ni < 4; ++ni)
        #pragma unroll
        for (int r = 0; r < 4; ++r)
          Qx[(size_t)(crow + mi * 16 + r) * 1024 + ccol + ni * 16] = __float2bfloat16(acc[mi][ni][r]);
  } else {
    #pragma unroll
    for (int mi = 0; mi < 8; ++mi) {
      const int rowbase = crow + mi * 16;  // multiple of 4 -> 8B-aligned dest
      #pragma unroll
      for (int ni = 0; ni < 4; ++ni) {
        const int vc = ccol + ni * 16 - 1024;
        __align__(8) __hip_bfloat16 o[4];
        #pragma unroll
        for (int r = 0; r < 4; ++r) o[r] = __float2bfloat16(acc[mi][ni][r]);
        *(uint2*)(Vt + (size_t)vc * M + rowbase) = *(const uint2*)o;
      }
    }
  }
}

// ---------------- QK^T gemm, fused exp epilogue + atomic row sums ----------
__global__ __launch_bounds__(512) void gemm_qk_exp(
    const __hip_bfloat16* __restrict__ A, int lda, long long sA,
    const __hip_bfloat16* __restrict__ B, int ldb, long long sB,
    __hip_bfloat16* __restrict__ Pv, int ldc, long long sC,
    float* __restrict__ Lsum, int ldl, int K)
{
  const int bz = blockIdx.z;
  GEMM_CORE256(A + (size_t)bz * sA, lda, B + (size_t)bz * sB, ldb, K)
  __hip_bfloat16* C = Pv + (size_t)bz * sC;
  float* Lrow = Lsum + (size_t)bz * ldl;
  #pragma unroll
  for (int mi = 0; mi < 8; ++mi) {
    #pragma unroll
    for (int r = 0; r < 4; ++r) {
      float s = 0.f;
      #pragma unroll
      for (int ni = 0; ni < 4; ++ni) {
        const float e = __expf(acc[mi][ni][r] * 0.125f);
        const __hip_bfloat16 h = __float2bfloat16(e);
        C[(size_t)(crow + mi * 16 + r) * ldc + ccol + ni * 16] = h;
        s += __bfloat162float(h);
      }
      #pragma unroll
      for (int mask = 1; mask < 16; mask <<= 1) s += __shfl_xor(s, mask);
      if (m16 == 0) atomicAdd(&Lrow[crow + mi * 16 + r], s);
    }
  }
}

// ---------------- PV gemm -> FINAL output: f32 * (1/l) + bias ---------------
__global__ __launch_bounds__(512) void gemm_pv_out(
    const __hip_bfloat16* __restrict__ A, int lda, long long sA,
    const __hip_bfloat16* __restrict__ B, int ldb, long long sB,
    float* __restrict__ Cv, int ldc, long long sC,
    const float* __restrict__ bias, const float* __restrict__ rsum, int K)
{
  const int bz = blockIdx.z;
  GEMM_CORE256(A + (size_t)bz * sA, lda, B + (size_t)bz * sB, ldb, K)
  float* C = Cv + (size_t)bz * sC;
  const float* rs = rsum + (size_t)bz * 2048;
  float bv[4];
  #pragma unroll
  for (int ni = 0; ni < 4; ++ni) bv[ni] = bias[ccol + ni * 16];
  #pragma unroll
  for (int mi = 0; mi < 8; ++mi) {
    float sc[4];
    #pragma unroll
    for (int r = 0; r < 4; ++r) sc[r] = 1.f / rs[crow + mi * 16 + r];
    #pragma unroll
    for (int ni = 0; ni < 4; ++ni)
      #pragma unroll
      for (int r = 0; r < 4; ++r)
        C[(size_t)(crow + mi * 16 + r) * ldc + ccol + ni * 16] =
            acc[mi][ni][r] * sc[r] + bv[ni];
  }
}

// ---------------------------------------------------------------------------
extern "C" void kernel_launch(void* const* d_in, const int* in_sizes, int n_in,
                              void* d_out, int out_size, void* d_ws, size_t ws_size,
                              hipStream_t stream) {
  const float* x     = (const float*)d_in[0];   // [8, 2048, 1024]
  const float* w_qkv = (const float*)d_in[1];   // [3072, 1024]
  const float* w_out = (const float*)d_in[2];   // [1024, 1024]
  const float* b_out = (const float*)d_in[3];   // [1024]
  float* out = (float*)d_out;

  constexpr int Bz = 8, N = 2048, D = 1024;
  constexpr int M = Bz * N;  // 16384
  constexpr size_t SLOT = (size_t)1024 * 1024;  // elems per 1024x1024 mat

  // ---- workspace ----
  // slots: 0 WkT | 1 Wob | 2 WqT | 3 WvT | 4 W~T | 5 Wc   (bf16, 12.6 MB)
  // then Xb [M,D] + Qx [M,D] + Vt [D,M] (bf16) + L [M] f32 + dyn P' (G*8.4MB)
  __hip_bfloat16* wsb = (__hip_bfloat16*)d_ws;
  __hip_bfloat16* WkT = wsb;
  __hip_bfloat16* WqT = wsb + 2 * SLOT;
  __hip_bfloat16* Wob = wsb + 1 * SLOT;
  __hip_bfloat16* Wt  = wsb + 4 * SLOT;
  char* p = (char*)(wsb + 6 * SLOT);
  __hip_bfloat16* Xb = (__hip_bfloat16*)p; p += (size_t)M * D * 2;
  __hip_bfloat16* Qx = (__hip_bfloat16*)p; p += (size_t)M * D * 2;
  __hip_bfloat16* Vt = (__hip_bfloat16*)p; p += (size_t)M * D * 2;
  float*          L  = (float*)p;          p += (size_t)M * 4;
  char* dyn = p;
  const size_t fixed_sz = (size_t)(dyn - (char*)d_ws);

  int G = 1;
  for (int g = 8; g >= 1; g >>= 1) {
    size_t dyn_sz = (size_t)g * N * N * 2;  // P' bf16
    if (fixed_sz + dyn_sz <= ws_size) { G = g; break; }
  }
  __hip_bfloat16* P = (__hip_bfloat16*)dyn;

  // phase 0: casts + weight pre-contraction
  hipMemsetAsync(L, 0, (size_t)M * 4, stream);
  cast_f32_bf16<<<(M * D) / (8 * 256), 256, 0, stream>>>(x, Xb, M * D);
  tcast<<<dim3(16, 16, 3), 256, 0, stream>>>(w_qkv, wsb);
  cast_f32_bf16<<<(D * D) / (8 * 256), 256, 0, stream>>>(w_out, Wob, D * D);
  // z=0: W~T = WkT @ WqT^T ; z=1: Wc = Wob @ WvT^T   (slot-stride batching)
  gemm_small<<<dim3(8, 8, 2), 256, 0, stream>>>(
      WkT, D, (long long)SLOT, WqT, D, (long long)SLOT, Wt, D, (long long)SLOT, D);

  // phase 1: Qx = Xb @ W~ ; Vt = (Xb @ Wc^T)^T  (B = [W~T ; Wc], 2048 rows)
  gemm_qv<<<dim3(8, M / 256), 512, 0, stream>>>(Xb, D, Wt, D, Qx, Vt, M, D);

  // phases 2-3: batched attention, groups of G
  for (int g = 0; g < Bz / G; ++g) {
    const size_t goff = (size_t)g * G * N;
    // P' = exp(Qx @ Xb^T * 0.125) (bf16) + atomic row sums into L
    gemm_qk_exp<<<dim3(N / 256, N / 256, G), 512, 0, stream>>>(
        Qx + goff * D, D, (long long)N * D,
        Xb + goff * D, D, (long long)N * D,
        P, N, (long long)N * N,
        L + goff, N, D);
    // y = (P' @ Vt^T)/l + b  -> final f32 output
    gemm_pv_out<<<dim3(D / 256, N / 256, G), 512, 0, stream>>>(
        P, N, (long long)N * N,
        Vt + goff, M, (long long)N,
        out + goff * D, D, (long long)N * D,
        b_out, L + goff, N);
  }
}